// Round 1
// 575.818 us; speedup vs baseline: 1.0114x; 1.0114x over previous
//
#include <hip/hip_runtime.h>

// TriangleMultiplicativeModule, MI355X/gfx950.
// Pipeline: kW (weights->bf16 transposed) ; kA (LN + 5 proj + sigmoid/mask,
// writes left_v/right_v as [d][i][k] bf16 + gate [p][d] bf16) ;
// kB (128 per-d 512^3 bf16 MFMA GEMMs -> out_t[d][i][j]) ;
// kC (LN over d * gate, GEMM @ W_out -> fp32 out).
// Workspace requirement: 262144 + 4*67108864 = 268,697,600 bytes.
//
// R1: kA occupancy-capped (71KB LDS -> 2 blocks/CU). Fixed by aliasing tmp onto
// xs (36.3KB -> 4 blocks/CU).
// R2: __launch_bounds__(256,4) pin forced VGPR 116->64 -> massive scratch
// spills (FETCH +103MB, WRITE +188MB), net regression. R3: keep LDS alias,
// drop the pin — VGPR 116 naturally supports 4 waves/EU.
// R4: kA phase-1 was latency-bound: 64-lane scattered 16B x-loads (rows 256KB
// apart -> 64 line probes per instr, MSHR exhaustion; all pipes <25% busy).
// Replaced with per-lane-addressed global_load_lds staging: each instr reads
// 2 complete 512B row segments (coalesced), wave-private 16-row rounds aliased
// on tmp (LDS stays 36352B -> 4 blocks/CU). XOR-swizzled via pre-swizzled
// global source; LN stats + af fragments built from LDS; xs bf16 buffer gone.

#define NN 512
#define DD 128
#define PT (NN * NN) // 262144

typedef float f4 __attribute__((ext_vector_type(4)));
typedef __bf16 bf8 __attribute__((ext_vector_type(8)));
typedef unsigned short u16;
typedef unsigned int u32;
typedef u16 us4 __attribute__((ext_vector_type(4)));
typedef u16 us8 __attribute__((ext_vector_type(8)));

__device__ __forceinline__ u16 f2bf(float f) {
    u32 u = __float_as_uint(f);
    return (u16)((u + 0x7fffu + ((u >> 16) & 1u)) >> 16); // RNE
}
__device__ __forceinline__ float bf2f(u16 h) { return __uint_as_float(((u32)h) << 16); }
__device__ __forceinline__ float sigm(float x) {
    return __builtin_amdgcn_rcpf(1.0f + __builtin_amdgcn_exp2f(-1.4426950408889634f * x));
}
__device__ __forceinline__ f4 mfma16(bf8 a, bf8 b, f4 c) {
    return __builtin_amdgcn_mfma_f32_16x16x32_bf16(a, b, c, 0, 0, 0);
}
__device__ __forceinline__ void async16(u16* lds, const u16* g) {
    __builtin_amdgcn_global_load_lds((const __attribute__((address_space(1))) u32*)(const void*)g,
                                     (__attribute__((address_space(3))) u32*)(void*)lds, 16, 0, 0);
}

// ---------------- kW: transpose+cast 6 weight matrices to bf16 [n][k] ----------------
__global__ __launch_bounds__(256) void kW(const float* __restrict__ wlg, const float* __restrict__ wl,
                                          const float* __restrict__ wrg, const float* __restrict__ wr,
                                          const float* __restrict__ wog, const float* __restrict__ wout,
                                          u16* __restrict__ wt, u16* __restrict__ wtout) {
    __shared__ float tile[128 * 129];
    const float* srcs[6] = {wlg, wl, wrg, wr, wog, wout};
    const int b = blockIdx.x;
    const float* s = srcs[b];
    u16* dst = (b < 5) ? (wt + b * 16384) : wtout;
    const int t = threadIdx.x;
    for (int idx = t; idx < 16384; idx += 256) {
        int k = idx >> 7, n = idx & 127;
        tile[k * 129 + n] = s[idx];
    }
    __syncthreads();
    for (int idx = t; idx < 16384; idx += 256) {
        int n = idx >> 7, k = idx & 127;
        dst[n * 128 + k] = f2bf(tile[k * 129 + n]); // Wt[n][k] = W[k][n]
    }
}

// ---------------- kA: layernorm + 5 projections (fused) ----------------
// Block = fixed i, 128 consecutive k (rows p = (k0+rr)*512 + i_blk).
// Phase 1 (R4): wave-private coalesced staging of x via global_load_lds
// (2 rounds x 16 rows, region aliased on tmp), LN stats + af frags from LDS.
// Writes left_v/right_v[d][i][k] (k-contiguous) via LDS transpose; gate [p][d] natural.
__global__ __launch_bounds__(256) void kA(const float* __restrict__ x, const float* __restrict__ smask,
                                          const float* __restrict__ nsc, const float* __restrict__ nbi,
                                          const float* __restrict__ b_l, const float* __restrict__ b_r,
                                          const float* __restrict__ b_lg, const float* __restrict__ b_rg,
                                          const float* __restrict__ b_og, const u16* __restrict__ wt,
                                          u16* __restrict__ left_v, u16* __restrict__ right_v,
                                          u16* __restrict__ gate) {
    __shared__ u16 xs[128 * 136];  // phase1: fp32 stage (4 waves x 16 rows x 512B = 32KB); g-loop: tmp
    __shared__ float ns[128], nb[128], smk[128];
    u16* tmp = xs;            // alias: stage is dead once af fragments are in registers
    float* stg = (float*)xs;  // wave w region at float offset w*2048 (16 rows x 128 floats)

    const int t = threadIdx.x;
    const int bid = blockIdx.x;
    const int i_blk = bid & 511;
    const int k0 = (bid >> 9) << 7;
    const int lane = t & 63, w = t >> 6;
    const int m = lane & 15, q = lane >> 4;

    if (t < 128) { ns[t] = nsc[t]; nb[t] = nbi[t]; smk[t] = smask[k0 + t]; }
    const float mi = smask[i_blk];

    // Issue round 0: rows w*32 + 0..15, one instr = 2 complete 512B row segments.
    // LDS dest linear (wave-uniform base + lane*16); global src pre-swizzled so
    // LDS[rl][slot s] holds row chunk (s ^ (rl&7)) -> conflict-free-ish reads.
#pragma unroll
    for (int it = 0; it < 8; ++it) {
        const int rl = it * 2 + (lane >> 5);
        const int c = (lane & 31) ^ (rl & 7);
        const float* gp = x + ((long)(k0 + w * 32 + rl) * NN + i_blk) * DD + c * 4;
        async16((u16*)(stg + w * 2048 + it * 256), (const u16*)gp);
    }

    bf8 af[2][4]; // A-fragments (shared by all 5 weights)
#pragma unroll
    for (int rd = 0; rd < 2; ++rd) {
        if (rd == 0) {
            __syncthreads(); // drains round-0 vmcnt; ns/nb/smk visible
        } else {
            // all round-0 LDS reads must retire before round-1 data can land
            asm volatile("s_waitcnt lgkmcnt(0)" ::: "memory");
            __builtin_amdgcn_sched_barrier(0);
#pragma unroll
            for (int it = 0; it < 8; ++it) {
                const int rl = it * 2 + (lane >> 5);
                const int c = (lane & 31) ^ (rl & 7);
                const float* gp = x + ((long)(k0 + w * 32 + 16 + rl) * NN + i_blk) * DD + c * 4;
                async16((u16*)(stg + w * 2048 + it * 256), (const u16*)gp);
            }
            asm volatile("s_waitcnt vmcnt(0)" ::: "memory"); // wave-private: no barrier needed
            __builtin_amdgcn_sched_barrier(0);
        }
        const float* wbase = stg + w * 2048;
        // stats: 4 lanes per row (rl_s = lane>>2), 32 floats each
        const int rl_s = lane >> 2, h2 = lane & 3;
        float s = 0.f, ss = 0.f;
        f4 vv[8];
#pragma unroll
        for (int q2 = 0; q2 < 8; ++q2)
            vv[q2] = ((const f4*)(wbase + rl_s * 128))[(h2 * 8 + q2) ^ (rl_s & 7)];
#pragma unroll
        for (int q2 = 0; q2 < 8; ++q2)
#pragma unroll
            for (int e = 0; e < 4; ++e) { float f = vv[q2][e]; s += f; ss += f * f; }
        s += __shfl_xor(s, 1); ss += __shfl_xor(ss, 1);
        s += __shfl_xor(s, 2); ss += __shfl_xor(ss, 2);
        const float mu = s * (1.f / 128.f);
        const float rstd = rsqrtf(ss * (1.f / 128.f) - mu * mu + 1e-6f);
        // broadcast stats of row m to this lane (stats for row r live in lanes 4r..4r+3)
        const float muM = __shfl(mu, m << 2);
        const float rsM = __shfl(rstd, m << 2);
        // af fragments: row = w*32 + rd*16 + m (region row m), k = kc*32+q*8+j
#pragma unroll
        for (int kc = 0; kc < 4; ++kc) {
            const int c0 = kc * 8 + q * 2;
            const f4* rowp = (const f4*)(wbase + m * 128);
            f4 x0 = rowp[c0 ^ (m & 7)];
            f4 x1 = rowp[(c0 + 1) ^ (m & 7)];
            f4 s0 = ((const f4*)ns)[c0], s1 = ((const f4*)ns)[c0 + 1];
            f4 b0 = ((const f4*)nb)[c0], b1 = ((const f4*)nb)[c0 + 1];
            us8 pk;
#pragma unroll
            for (int e = 0; e < 4; ++e) {
                pk[e] = f2bf((x0[e] - muM) * rsM * s0[e] + b0[e]);
                pk[e + 4] = f2bf((x1[e] - muM) * rsM * s1[e] + b1[e]);
            }
            af[rd][kc] = *(const bf8*)&pk;
        }
    }
    __syncthreads(); // af in registers; stage dead -> tmp reusable by all waves

#pragma unroll
    for (int g = 0; g < 3; ++g) {
        const u16* wg = wt + (g == 0 ? 0 : (g == 1 ? 2 * 16384 : 4 * 16384));
        const float* bg = (g == 0) ? b_lg : (g == 1 ? b_rg : b_og);
        f4 accG[16];
#pragma unroll
        for (int nt = 0; nt < 8; ++nt) {
            bf8 bfr[4];
#pragma unroll
            for (int kc = 0; kc < 4; ++kc)
                bfr[kc] = *(const bf8*)(wg + (nt * 16 + m) * 128 + kc * 32 + q * 8);
#pragma unroll
            for (int st = 0; st < 2; ++st) {
                f4 a = {0.f, 0.f, 0.f, 0.f};
#pragma unroll
                for (int kc = 0; kc < 4; ++kc) a = mfma16(af[st][kc], bfr[kc], a);
                accG[nt * 2 + st] = a;
            }
        }
        if (g < 2) { // gated value -> transposed store (tmp as [d][rr])
            const u16* wv = wt + (g == 0 ? 1 : 3) * 16384;
            const float* bv = (g == 0) ? b_l : b_r;
#pragma unroll
            for (int nt = 0; nt < 8; ++nt) {
                bf8 bfr[4];
#pragma unroll
                for (int kc = 0; kc < 4; ++kc)
                    bfr[kc] = *(const bf8*)(wv + (nt * 16 + m) * 128 + kc * 32 + q * 8);
                const int d = nt * 16 + m;
                const float bvn = bv[d], bgn = bg[d];
#pragma unroll
                for (int st = 0; st < 2; ++st) {
                    f4 a = {0.f, 0.f, 0.f, 0.f};
#pragma unroll
                    for (int kc = 0; kc < 4; ++kc) a = mfma16(af[st][kc], bfr[kc], a);
                    const int rr0 = (w * 2 + st) * 16 + q * 4;
                    us4 pk;
#pragma unroll
                    for (int r = 0; r < 4; ++r) {
                        float gv = sigm(accG[nt * 2 + st][r] + bgn);
                        pk[r] = f2bf((a[r] + bvn) * (smk[rr0 + r] * mi) * gv);
                    }
                    *(us4*)&tmp[d * 136 + rr0] = pk;
                }
            }
        } else { // ogate -> natural store (tmp as [rr][d])
#pragma unroll
            for (int nt = 0; nt < 8; ++nt) {
                const int d = nt * 16 + m;
                const float bgn = bg[d];
#pragma unroll
                for (int st = 0; st < 2; ++st) {
                    const int rr0 = (w * 2 + st) * 16 + q * 4;
#pragma unroll
                    for (int r = 0; r < 4; ++r)
                        tmp[(rr0 + r) * 136 + d] = f2bf(sigm(accG[nt * 2 + st][r] + bgn));
                }
            }
        }
        __syncthreads();
        if (g < 2) { // cooperative transposed store: [d][i][k], 256B runs per d
            u16* dst = (g == 0) ? left_v : right_v;
#pragma unroll
            for (int r8 = 0; r8 < 8; ++r8) {
                const int d = (t >> 4) + r8 * 16;
                const int mc = t & 15;
                us8 vv = *(const us8*)&tmp[d * 136 + mc * 8];
                *(us8*)(dst + (long)d * PT + (long)i_blk * NN + k0 + mc * 8) = vv;
            }
        } else { // gate natural [p][d]
#pragma unroll
            for (int r8 = 0; r8 < 8; ++r8) {
                const int rrr = (t >> 4) + r8 * 16;
                const int dc = t & 15;
                us8 vv = *(const us8*)&tmp[rrr * 136 + dc * 8];
                *(us8*)(gate + ((long)(k0 + rrr) * NN + i_blk) * DD + dc * 8) = vv;
            }
        }
        __syncthreads();
    }
}

// ---------------- kB: per-d 512x512x512 bf16 GEMM, C_d = Lv_d * Rv_d^T ----------------
// grid = 128 d * 16 (4x4 128-tiles). m97 structure: global_load_lds 16B staging,
// XOR-swizzled 16B chunks so frag ds_read_b128 is 2-way (free).
__global__ __launch_bounds__(256) void kB(const u16* __restrict__ left_v, const u16* __restrict__ right_v,
                                          u16* __restrict__ out_t) {
    __shared__ u16 smem[128 * 136]; // As[128][32] | Bs[128][32] ; epilogue reuses all as ct[128][136]
    u16* As = smem;
    u16* Bs = smem + 4096;
    const int t = threadIdx.x, lane = t & 63, w = t >> 6;
    const int bid = blockIdx.x;
    const int d = bid >> 4;
    const int ti = (bid & 3) * 128;
    const int tj = ((bid >> 2) & 3) * 128;
    const long dbase = (long)d * PT;
    const int frow = lane >> 2;                      // staging row within 16
    const int fc = (lane & 3) ^ ((lane >> 3) & 3);   // swizzled global 16B chunk
    const int m = lane & 15, q = lane >> 4;
    const int sl = q ^ ((m >> 1) & 3); // frag slot (matches staging swizzle)
    const int mrow0 = (w & 1) * 64;
    const int nrow0 = (w >> 1) * 64;

    f4 zero = {0.f, 0.f, 0.f, 0.f};
    f4 acc[16];
#pragma unroll
    for (int z = 0; z < 16; ++z) acc[z] = zero;

    const u16* Agb = left_v + dbase + (long)ti * NN;
    const u16* Bgb = right_v + dbase + (long)tj * NN;

    for (int ks = 0; ks < 16; ++ks) {
        __syncthreads();
#pragma unroll
        for (int inst = 0; inst < 2; ++inst) {
            const int rbase = w * 32 + inst * 16;
            const int row = rbase + frow;
            async16(As + rbase * 32, Agb + (long)row * NN + ks * 32 + fc * 8);
            async16(Bs + rbase * 32, Bgb + (long)row * NN + ks * 32 + fc * 8);
        }
        __syncthreads();
        bf8 af[4], bfv[4];
#pragma unroll
        for (int mt = 0; mt < 4; ++mt) af[mt] = *(const bf8*)&As[(mrow0 + mt * 16 + m) * 32 + sl * 8];
#pragma unroll
        for (int nt = 0; nt < 4; ++nt) bfv[nt] = *(const bf8*)&Bs[(nrow0 + nt * 16 + m) * 32 + sl * 8];
#pragma unroll
        for (int mt = 0; mt < 4; ++mt)
#pragma unroll
            for (int nt = 0; nt < 4; ++nt) acc[mt * 4 + nt] = mfma16(af[mt], bfv[nt], acc[mt * 4 + nt]);
    }
    __syncthreads();
    u16* ct = smem; // [128][136]
#pragma unroll
    for (int mt = 0; mt < 4; ++mt)
#pragma unroll
        for (int nt = 0; nt < 4; ++nt) {
            const int row0 = mrow0 + mt * 16 + q * 4;
            const int col = nrow0 + nt * 16 + m;
            f4 a = acc[mt * 4 + nt];
#pragma unroll
            for (int r = 0; r < 4; ++r) ct[(row0 + r) * 136 + col] = f2bf(a[r]);
        }
    __syncthreads();
#pragma unroll
    for (int r8 = 0; r8 < 8; ++r8) {
        const int row = (t >> 4) + r8 * 16;
        const int mc = t & 15;
        us8 vv = *(const us8*)&ct[row * 136 + mc * 8];
        *(us8*)(out_t + dbase + (long)(ti + row) * NN + tj + mc * 8) = vv;
    }
}

// ---------------- kC: LN over d * gate, then @ W_out + b_out ----------------
// Block = fixed i, 128 j. Stages out_t into chunk-swizzled os[j][d] (4-way max
// on the u16 scatter via e-permutation; frag reads 2-way/free).
__global__ __launch_bounds__(256) void kC(const u16* __restrict__ out_t, const u16* __restrict__ gate,
                                          const float* __restrict__ osc_g, const float* __restrict__ obi_g,
                                          const u16* __restrict__ wtout, const float* __restrict__ b_out,
                                          float* __restrict__ out) {
    __shared__ u16 os[128 * 128]; // rows 256B, 16B chunks at slot = (d>>3) ^ (j&15)
    __shared__ float osc[128], obi[128];
    const int t = threadIdx.x;
    const int bid = blockIdx.x;
    const int i = bid >> 2;
    const int j0 = (bid & 3) * 128;
    if (t < 128) { osc[t] = osc_g[t]; obi[t] = obi_g[t]; }
    const long p0 = (long)i * NN + j0;

#pragma unroll
    for (int r8 = 0; r8 < 8; ++r8) { // stage + transpose
        const int dd = (t >> 4) + r8 * 16;
        const int mm = t & 15;
        us8 vv = *(const us8*)(out_t + (long)dd * PT + (long)i * NN + j0 + mm * 8);
        const int cd = dd >> 3, dl = dd & 7;
#pragma unroll
        for (int e = 0; e < 8; ++e) {
            const int ee = e ^ (mm & 7); // spread banks across lanes
            const int j = mm * 8 + ee;
            os[j * 128 + ((cd ^ (j & 15)) << 3) + dl] = vv[ee];
        }
    }
    __syncthreads();
    { // LN * gate, in place
        const int j = t >> 1, h = t & 1;
        const long p = p0 + j;
        float s = 0.f, ss = 0.f;
#pragma unroll
        for (int cc = 0; cc < 8; ++cc) {
            const int cd = h * 8 + cc;
            us8 vv = *(const us8*)&os[j * 128 + ((cd ^ (j & 15)) << 3)];
#pragma unroll
            for (int e = 0; e < 8; ++e) { float f = bf2f(vv[e]); s += f; ss += f * f; }
        }
        s += __shfl_xor(s, 1); ss += __shfl_xor(ss, 1);
        const float mu = s * (1.f / 128.f);
        const float rstd = rsqrtf(ss * (1.f / 128.f) - mu * mu + 1e-6f);
#pragma unroll
        for (int cc = 0; cc < 8; ++cc) {
            const int cd = h * 8 + cc;
            u16* slotp = &os[j * 128 + ((cd ^ (j & 15)) << 3)];
            us8 vv = *(const us8*)slotp;
            us8 gv = *(const us8*)(gate + p * DD + cd * 8);
            us8 rv;
#pragma unroll
            for (int e = 0; e < 8; ++e) {
                const int d2 = cd * 8 + e;
                float f = (bf2f(vv[e]) - mu) * rstd * osc[d2] + obi[d2];
                rv[e] = f2bf(f * bf2f(gv[e]));
            }
            *(us8*)slotp = rv;
        }
    }
    __syncthreads();
    const int lane = t & 63, w = t >> 6;
    const int m = lane & 15, q = lane >> 4;
    bf8 af[2][4];
#pragma unroll
    for (int st = 0; st < 2; ++st) {
        const int jr = (w * 2 + st) * 16 + m;
#pragma unroll
        for (int kc = 0; kc < 4; ++kc) {
            const int cd = kc * 4 + q;
            af[st][kc] = *(const bf8*)&os[jr * 128 + ((cd ^ (jr & 15)) << 3)];
        }
    }
#pragma unroll
    for (int nt = 0; nt < 8; ++nt) {
        bf8 bfr[4];
#pragma unroll
        for (int kc = 0; kc < 4; ++kc)
            bfr[kc] = *(const bf8*)(wtout + (nt * 16 + m) * 128 + kc * 32 + q * 8);
        const float bo = b_out[nt * 16 + m];
#pragma unroll
        for (int st = 0; st < 2; ++st) {
            f4 a = {0.f, 0.f, 0.f, 0.f};
#pragma unroll
            for (int kc = 0; kc < 4; ++kc) a = mfma16(af[st][kc], bfr[kc], a);
            const int rr0 = (w * 2 + st) * 16 + q * 4;
#pragma unroll
            for (int r = 0; r < 4; ++r) out[(p0 + rr0 + r) * DD + nt * 16 + m] = a[r] + bo;
        }
    }
}

extern "C" void kernel_launch(void* const* d_in, const int* in_sizes, int n_in, void* d_out, int out_size,
                              void* d_ws, size_t ws_size, hipStream_t stream) {
    const float* x = (const float*)d_in[0];
    const float* sm = (const float*)d_in[1];
    const float* nsc = (const float*)d_in[2];
    const float* nbi = (const float*)d_in[3];
    const float* wl = (const float*)d_in[4];
    const float* bl = (const float*)d_in[5];
    const float* wr = (const float*)d_in[6];
    const float* br = (const float*)d_in[7];
    const float* wlg = (const float*)d_in[8];
    const float* blg = (const float*)d_in[9];
    const float* wrg = (const float*)d_in[10];
    const float* brg = (const float*)d_in[11];
    const float* wog = (const float*)d_in[12];
    const float* bog = (const float*)d_in[13];
    const float* onsc = (const float*)d_in[14];
    const float* onbi = (const float*)d_in[15];
    const float* wout = (const float*)d_in[16];
    const float* bout = (const float*)d_in[17];

    char* ws = (char*)d_ws;
    u16* wt = (u16*)ws;                 // 5*128*128 bf16
    u16* wtout = (u16*)(ws + 163840);   // 128*128 bf16
    u16* left_v = (u16*)(ws + 262144);  // [128][512][512] bf16
    u16* right_v = left_v + (long)DD * PT;
    u16* gate = right_v + (long)DD * PT;
    u16* out_t = gate + (long)DD * PT;  // total 268,697,600 B

    kW<<<6, 256, 0, stream>>>(wlg, wl, wrg, wr, wog, wout, wt, wtout);
    kA<<<2048, 256, 0, stream>>>(x, sm, nsc, nbi, bl, br, blg, brg, bog, wt, left_v, right_v, gate);
    kB<<<2048, 256, 0, stream>>>(left_v, right_v, out_t);
    kC<<<2048, 256, 0, stream>>>(out_t, gate, onsc, onbi, wtout, bout, (float*)d_out);
}